// Round 6
// baseline (409.683 us; speedup 1.0000x reference)
//
#include <hip/hip_runtime.h>
#include <hip/hip_bf16.h>

typedef __bf16 bf16x8 __attribute__((ext_vector_type(8)));
typedef __bf16 bf16x4 __attribute__((ext_vector_type(4)));
typedef short  s16x4  __attribute__((ext_vector_type(4)));
typedef float  f32x4  __attribute__((ext_vector_type(4)));
typedef unsigned short u16x8 __attribute__((ext_vector_type(8)));
typedef unsigned short USHORT;

__device__ __forceinline__ USHORT f2bf(float f) {
    unsigned u = __float_as_uint(f);
    u += 0x7fffu + ((u >> 16) & 1u);
    return (USHORT)(u >> 16);
}

__device__ __forceinline__ unsigned pack2bf(float x, float y) {
    union { __hip_bfloat162 h; unsigned u; } c;
    c.h = __float22bfloat162_rn(float2{x, y});
    return c.u;
}

__device__ __forceinline__ f32x4 fz4() { f32x4 z = {0.f, 0.f, 0.f, 0.f}; return z; }

__device__ __forceinline__ bf16x8 ldbf8(const USHORT* p) { return *(const bf16x8*)p; }

__device__ __forceinline__ f32x4 mfma16(bf16x8 a, bf16x8 b, f32x4 c) {
    return __builtin_amdgcn_mfma_f32_16x16x32_bf16(a, b, c, 0, 0, 0);
}

// K=16 MFMA: A/B = 4 bf16 (2 VGPRs). B layout (n=l16, k=quad*4+j) matches the
// C/D layout of the score MFMA (col=l16, row=quad*4+r) -> direct register PV.
__device__ __forceinline__ f32x4 mfma16k16(bf16x4 a, bf16x4 b, f32x4 c) {
#if __has_builtin(__builtin_amdgcn_mfma_f32_16x16x16_bf16)
    return __builtin_amdgcn_mfma_f32_16x16x16_bf16(a, b, c, 0, 0, 0);
#else
    return __builtin_amdgcn_mfma_f32_16x16x16bf16_1k(
        __builtin_bit_cast(s16x4, a), __builtin_bit_cast(s16x4, b), c, 0, 0, 0);
#endif
}

// async global->LDS, 16B per lane; LDS dest is wave-uniform base + lane*16
__device__ __forceinline__ void gload_lds16(const void* g, void* s) {
    __builtin_amdgcn_global_load_lds(
        (const __attribute__((address_space(1))) unsigned int*)g,
        (__attribute__((address_space(3))) unsigned int*)s, 16, 0, 0);
}

// ---------------- merged prep: X cvt + W transposes + ctx zero -----------------
__global__ __launch_bounds__(256) void prep_kernel(const float* __restrict__ X,
                                                   const float* __restrict__ Wqkv,
                                                   const float* __restrict__ Wout,
                                                   USHORT* __restrict__ Xb,
                                                   USHORT* __restrict__ Wt1,
                                                   USHORT* __restrict__ Wt3,
                                                   float* __restrict__ ctx) {
    int bid = blockIdx.x;
    if (bid < 2048) {
        int base = (bid * 256 + threadIdx.x) * 8;
        float4 a = *(const float4*)(X + base);
        float4 b = *(const float4*)(X + base + 4);
        u16x8 o;
        o[0] = f2bf(a.x); o[1] = f2bf(a.y); o[2] = f2bf(a.z); o[3] = f2bf(a.w);
        o[4] = f2bf(b.x); o[5] = f2bf(b.y); o[6] = f2bf(b.z); o[7] = f2bf(b.w);
        *(u16x8*)(Xb + base) = o;
    } else if (bid < 3328) {
        int t = (bid - 2048) * 256 + threadIdx.x;   // 640x512
        int k = t & 511, n = t >> 9;
        Wt1[t] = f2bf(Wqkv[(size_t)k * 1536 + n]);
    } else if (bid < 4352) {
        int t = (bid - 3328) * 256 + threadIdx.x;   // 512x512
        int k = t & 511, n = t >> 9;
        Wt3[t] = f2bf(Wout[(size_t)k * 512 + n]);
    } else {
        int base = ((bid - 4352) * 256 + threadIdx.x) * 8;
        float4 z = {0.f, 0.f, 0.f, 0.f};
        *(float4*)(ctx + base) = z;
        *(float4*)(ctx + base + 4) = z;
    }
}

// ---------------- fp32 -> bf16 convert (8 elems/thread) ------------------------
__global__ __launch_bounds__(256) void cvt_f32_bf16(const float* __restrict__ src,
                                                    USHORT* __restrict__ dst) {
    int base = (blockIdx.x * 256 + threadIdx.x) * 8;
    float4 a = *(const float4*)(src + base);
    float4 b = *(const float4*)(src + base + 4);
    u16x8 o;
    o[0] = f2bf(a.x); o[1] = f2bf(a.y); o[2] = f2bf(a.z); o[3] = f2bf(a.w);
    o[4] = f2bf(b.x); o[5] = f2bf(b.y); o[6] = f2bf(b.z); o[7] = f2bf(b.w);
    *(u16x8*)(dst + base) = o;
}

// ---------------- m97-style bf16 GEMM: C = A(MxK) * Bt(NxK)^T -------------------
template <bool BF16OUT>
__global__ __launch_bounds__(256) void gemm_bt(const USHORT* __restrict__ A,
                                               const USHORT* __restrict__ Bt,
                                               void* __restrict__ Cv,
                                               int M, int N, int K) {
    __shared__ __align__(16) USHORT Asm[128 * 32];
    __shared__ __align__(16) USHORT Bsm[128 * 32];
    const int tid = threadIdx.x;
    const int wv = tid >> 6, ln = tid & 63;
    const int l16 = ln & 15, quad = ln >> 4;
    const int m0 = blockIdx.x * 128, n0 = blockIdx.y * 128;
    const int wm = (wv >> 1) * 64, wn = (wv & 1) * 64;

    f32x4 acc[4][4];
#pragma unroll
    for (int i = 0; i < 4; ++i)
#pragma unroll
        for (int j = 0; j < 4; ++j) acc[i][j] = fz4();

    const int kTiles = K >> 5;
    for (int kt = 0; kt < kTiles; ++kt) {
        __syncthreads();
#pragma unroll
        for (int i = 0; i < 2; ++i) {
            int cb = wv * 128 + i * 64;
            int c = cb + ln;
            gload_lds16(A + (size_t)(m0 + (c >> 2)) * K + kt * 32 + (c & 3) * 8,
                        &Asm[cb * 8]);
            gload_lds16(Bt + (size_t)(n0 + (c >> 2)) * K + kt * 32 + (c & 3) * 8,
                        &Bsm[cb * 8]);
        }
        __syncthreads();

        bf16x8 af[4], bfr[4];
#pragma unroll
        for (int i = 0; i < 4; ++i)
            af[i] = ldbf8(&Asm[(wm + i * 16 + l16) * 32 + quad * 8]);
#pragma unroll
        for (int j = 0; j < 4; ++j)
            bfr[j] = ldbf8(&Bsm[(wn + j * 16 + l16) * 32 + quad * 8]);
#pragma unroll
        for (int i = 0; i < 4; ++i)
#pragma unroll
            for (int j = 0; j < 4; ++j)
                acc[i][j] = mfma16(af[i], bfr[j], acc[i][j]);
    }

#pragma unroll
    for (int i = 0; i < 4; ++i)
#pragma unroll
        for (int j = 0; j < 4; ++j)
#pragma unroll
            for (int r = 0; r < 4; ++r) {
                size_t row = m0 + wm + i * 16 + quad * 4 + r;
                size_t col = n0 + wn + j * 16 + l16;
                if (BF16OUT)
                    ((USHORT*)Cv)[row * N + col] = f2bf(acc[i][j][r]);
                else
                    ((float*)Cv)[row * N + col] = acc[i][j][r];
            }
}

// ---------------- V transpose: Vt[((b*8+h)*64+d)*1024+k] = P[(b*1024+k)*640+(h+2)*64+d]
__global__ __launch_bounds__(256) void transpose_v(const USHORT* __restrict__ P,
                                                   USHORT* __restrict__ Vt) {
    __shared__ __align__(16) USHORT T[64][72];
    const int t = threadIdx.x;
    const int k0 = blockIdx.x * 64;
    const int hh = blockIdx.y;
    const int b = blockIdx.z;
#pragma unroll
    for (int i = 0; i < 2; ++i) {
        int c = i * 256 + t;
        int kk = c >> 3, d8 = (c & 7) * 8;
        u16x8 v = *(const u16x8*)(P + (size_t)((b << 10) + k0 + kk) * 640 +
                                  (hh + 2) * 64 + d8);
        *(u16x8*)&T[kk][d8] = v;
    }
    __syncthreads();
#pragma unroll
    for (int i = 0; i < 2; ++i) {
        int d = (t >> 3) + i * 32;
        int kk0 = (t & 7) * 8;
        u16x8 v;
#pragma unroll
        for (int j = 0; j < 8; ++j) v[j] = T[kk0 + j][d];
        *(u16x8*)(Vt + (size_t)(((b << 3) + hh) * 64 + d) * 1024 + k0 + kk0) = v;
    }
}

// ---------------- fused attention v6: spill-free register budget ----------------
// v5 structure (staged K/V, transposed scores, register-direct K=16 PV) with
// Q residency evicted: the two Q fragments per (b,kt) are re-loaded from P
// (L2/L3-resident) right at their MFMA use. Peak VGPR demand ~80 (+128 AGPR
// oacc) — fits the 256-reg budget at 2 waves/SIMD with margin, no scratch.
// Q re-fetch cost: ~536 MB L2 reads over the kernel ~= 15 us at 34.5 TB/s,
// overlapped across 8 waves/CU; beats ~400 MB of HBM spill traffic.
__global__ __launch_bounds__(256, 2) void attn_kernel(const USHORT* __restrict__ P,
                                                      const USHORT* __restrict__ Vt,
                                                      float* __restrict__ ctx) {
    __shared__ __align__(16) USHORT Ksm[8][32][64];   // 32 KB
    __shared__ __align__(16) USHORT Vsm[8][64][32];   // 32 KB

    const int qb = blockIdx.x, h = blockIdx.y, kc = blockIdx.z;
    const int tid = threadIdx.x;
    const int wv = tid >> 6, ln = tid & 63;
    const int l16 = ln & 15, quad = ln >> 4;
    const int q0 = qb * 64 + wv * 16;

    // staging source coords (fixed per thread)
    const int rowK = wv * 8 + (ln >> 3);                          // 0..31
    const int cgK  = (ln & 7) ^ (rowK & 7);
    const int dV   = wv * 16 + (ln >> 2);                         // 0..63
    const int cgV  = (ln & 3) ^ (dV & 3) ^ ((dV >> 2) & 3);       // double-XOR

    // Q fragment base (B-operand K=32: n=q=l16, k=d=quad*8+j); batch stride 640K
    const USHORT* qbase = P + (size_t)(q0 + l16) * 640 + h * 64 + quad * 8;

    f32x4 oacc[8][4];
#pragma unroll
    for (int b = 0; b < 8; ++b)
#pragma unroll
        for (int nt = 0; nt < 4; ++nt) oacc[b][nt] = fz4();

    // PV V-read swizzle pieces (nt-independent)
    const int pvx = (l16 & 3) ^ ((l16 >> 2) & 3);
    const int pvh = (quad & 1) * 4;

    for (int it = 0; it < 8; ++it) {
        const int k0 = kc * 256 + it * 32;

        __syncthreads();  // prev-step LDS reads done before overwrite
        {
            const USHORT* pK = P + (size_t)(k0 + rowK) * 640 + (h + 1) * 64 + cgK * 8;
            const USHORT* pV = Vt + (size_t)(h * 64 + dV) * 1024 + k0 + cgV * 8;
            USHORT* sK = &Ksm[0][wv * 8][0];
            USHORT* sV = &Vsm[0][wv * 16][0];
#pragma unroll 1
            for (int b = 0; b < 8; ++b) {
                gload_lds16(pK, sK);
                gload_lds16(pV, sV);
                pK += 1024 * 640;       // batch stride in P
                pV += 8 * 64 * 1024;    // batch stride in Vt
                sK += 32 * 64;
                sV += 64 * 32;
            }
        }
        __syncthreads();  // drains vmcnt for global_load_lds

#pragma unroll 1
        for (int kt = 0; kt < 2; ++kt) {
            // ---- scores: S^T[key16][q16] per batch, K=32 MFMAs ----
            // Q fragments re-loaded from L2 at point of use (register economy).
            f32x4 sacc[8];
#pragma unroll
            for (int b = 0; b < 8; ++b) {
                const USHORT* qp = qbase + (size_t)b * (1024 * 640);
                bf16x8 kf0 = ldbf8(&Ksm[b][kt * 16 + l16][(quad ^ (l16 & 7)) * 8]);
                bf16x8 qf0 = ldbf8(qp);
                f32x4 s = mfma16(kf0, qf0, fz4());
                bf16x8 kf1 = ldbf8(&Ksm[b][kt * 16 + l16][((4 + quad) ^ (l16 & 7)) * 8]);
                bf16x8 qf1 = ldbf8(qp + 32);
                sacc[b] = mfma16(kf1, qf1, s);
            }

            // ---- softmax over batch axis (per-lane); exp2 in place ----
            f32x4 Zv = fz4();
#pragma unroll
            for (int b = 0; b < 8; ++b) {
#pragma unroll
                for (int r = 0; r < 4; ++r)
                    sacc[b][r] = __builtin_amdgcn_exp2f(sacc[b][r] * 0.1803368801f);
                Zv += sacc[b];
            }
            f32x4 inv;
#pragma unroll
            for (int r = 0; r < 4; ++r) inv[r] = __builtin_amdgcn_rcpf(Zv[r]);

            // ---- PV: attn (registers, B-operand of K=16 MFMA) x V^T ----
            const int pvc = (kt * 2 + (quad >> 1)) ^ pvx;   // physical 16B chunk
#pragma unroll
            for (int b = 0; b < 8; ++b) {
                f32x4 p = sacc[b] * inv;
                union { unsigned u[2]; bf16x4 v; } at;
                at.u[0] = pack2bf(p[0], p[1]);
                at.u[1] = pack2bf(p[2], p[3]);
#pragma unroll
                for (int nt = 0; nt < 4; ++nt) {
                    bf16x4 vf = *(const bf16x4*)&Vsm[b][nt * 16 + l16][pvc * 8 + pvh];
                    oacc[b][nt] = mfma16k16(vf, at.v, oacc[b][nt]);
                }
            }
        }
    }

    // O^T epilogue: lane holds 4 contiguous d per (b,nt) -> coalesced atomics
#pragma unroll
    for (int b = 0; b < 8; ++b)
#pragma unroll
        for (int nt = 0; nt < 4; ++nt) {
            float* base = ctx + (size_t)((b << 10) + q0 + l16) * 512 +
                          h * 64 + nt * 16 + quad * 4;
#pragma unroll
            for (int r = 0; r < 4; ++r)
                unsafeAtomicAdd(base + r, oacc[b][nt][r]);
        }
}

extern "C" void kernel_launch(void* const* d_in, const int* in_sizes, int n_in,
                              void* d_out, int out_size, void* d_ws, size_t ws_size,
                              hipStream_t stream) {
    const float* X = (const float*)d_in[0];     // (8,1024,512)
    const float* Wqkv = (const float*)d_in[1];  // (512,1536) — only cols 0..639 used
    const float* Wout = (const float*)d_in[2];  // (512,512)
    float* out = (float*)d_out;                 // (8,1024,512) fp32

    char* w = (char*)d_ws;
    USHORT* Xb  = (USHORT*)(w);              //  8,388,608 B (reused as CtxB later)
    USHORT* Wt1 = (USHORT*)(w + 8388608);    //    655,360 B  (640x512)
    USHORT* Wt3 = (USHORT*)(w + 9043968);    //    524,288 B  (512x512)
    USHORT* P   = (USHORT*)(w + 9568256);    // 10,485,760 B  (8192x640 bf16)
    USHORT* Vt  = (USHORT*)(w + 20054016);   //  8,388,608 B  (8x8x64x1024 bf16)
    float*  ctx = (float*)(w + 28442624);    // 16,777,216 B  (8192x512 fp32) end=45.2MB
    USHORT* CtxB = Xb;                       // Xb dead after GEMM1

    prep_kernel<<<6400, 256, 0, stream>>>(X, Wqkv, Wout, Xb, Wt1, Wt3, ctx);
    // P = Xb @ Wqkv[:, :640]
    gemm_bt<true><<<dim3(64, 5), 256, 0, stream>>>(Xb, Wt1, (void*)P, 8192, 640, 512);
    transpose_v<<<dim3(16, 8, 8), 256, 0, stream>>>(P, Vt);
    attn_kernel<<<dim3(16, 8, 4), 256, 0, stream>>>(P, Vt, ctx);
    cvt_f32_bf16<<<2048, 256, 0, stream>>>(ctx, CtxB);
    // out = ctx @ W_out
    gemm_bt<false><<<dim3(64, 4), 256, 0, stream>>>(CtxB, Wt3, (void*)out, 8192, 512, 512);
}

// Round 7
// 286.736 us; speedup vs baseline: 1.4288x; 1.4288x over previous
//
#include <hip/hip_runtime.h>
#include <hip/hip_bf16.h>

typedef __bf16 bf16x8 __attribute__((ext_vector_type(8)));
typedef __bf16 bf16x4 __attribute__((ext_vector_type(4)));
typedef short  s16x4  __attribute__((ext_vector_type(4)));
typedef float  f32x4  __attribute__((ext_vector_type(4)));
typedef unsigned short u16x8 __attribute__((ext_vector_type(8)));
typedef unsigned short USHORT;

__device__ __forceinline__ USHORT f2bf(float f) {
    unsigned u = __float_as_uint(f);
    u += 0x7fffu + ((u >> 16) & 1u);
    return (USHORT)(u >> 16);
}

__device__ __forceinline__ unsigned pack2bf(float x, float y) {
    union { __hip_bfloat162 h; unsigned u; } c;
    c.h = __float22bfloat162_rn(float2{x, y});
    return c.u;
}

__device__ __forceinline__ float bflo(unsigned u) { return __uint_as_float(u << 16); }
__device__ __forceinline__ float bfhi(unsigned u) { return __uint_as_float(u & 0xffff0000u); }

__device__ __forceinline__ f32x4 fz4() { f32x4 z = {0.f, 0.f, 0.f, 0.f}; return z; }

__device__ __forceinline__ bf16x8 ldbf8(const USHORT* p) { return *(const bf16x8*)p; }

__device__ __forceinline__ f32x4 mfma16(bf16x8 a, bf16x8 b, f32x4 c) {
    return __builtin_amdgcn_mfma_f32_16x16x32_bf16(a, b, c, 0, 0, 0);
}

// K=16 MFMA: B layout (n=l16, k=quad*4+j) == C/D layout of the score MFMA
// (col=l16, row=quad*4+r) -> softmaxed scores feed PV directly from registers.
__device__ __forceinline__ f32x4 mfma16k16(bf16x4 a, bf16x4 b, f32x4 c) {
#if __has_builtin(__builtin_amdgcn_mfma_f32_16x16x16_bf16)
    return __builtin_amdgcn_mfma_f32_16x16x16_bf16(a, b, c, 0, 0, 0);
#else
    return __builtin_amdgcn_mfma_f32_16x16x16bf16_1k(
        __builtin_bit_cast(s16x4, a), __builtin_bit_cast(s16x4, b), c, 0, 0, 0);
#endif
}

// async global->LDS, 16B per lane; LDS dest is wave-uniform base + lane*16
__device__ __forceinline__ void gload_lds16(const void* g, void* s) {
    __builtin_amdgcn_global_load_lds(
        (const __attribute__((address_space(1))) unsigned int*)g,
        (__attribute__((address_space(3))) unsigned int*)s, 16, 0, 0);
}

// ---------------- merged prep: X cvt + both W transposes -----------------------
__global__ __launch_bounds__(256) void prep_kernel(const float* __restrict__ X,
                                                   const float* __restrict__ Wqkv,
                                                   const float* __restrict__ Wout,
                                                   USHORT* __restrict__ Xb,
                                                   USHORT* __restrict__ Wt1,
                                                   USHORT* __restrict__ Wt3) {
    int bid = blockIdx.x;
    if (bid < 2048) {
        int base = (bid * 256 + threadIdx.x) * 8;
        float4 a = *(const float4*)(X + base);
        float4 b = *(const float4*)(X + base + 4);
        u16x8 o;
        o[0] = f2bf(a.x); o[1] = f2bf(a.y); o[2] = f2bf(a.z); o[3] = f2bf(a.w);
        o[4] = f2bf(b.x); o[5] = f2bf(b.y); o[6] = f2bf(b.z); o[7] = f2bf(b.w);
        *(u16x8*)(Xb + base) = o;
    } else if (bid < 3328) {
        int t = (bid - 2048) * 256 + threadIdx.x;   // 640x512
        int k = t & 511, n = t >> 9;
        Wt1[t] = f2bf(Wqkv[(size_t)k * 1536 + n]);
    } else {
        int t = (bid - 3328) * 256 + threadIdx.x;   // 512x512
        int k = t & 511, n = t >> 9;
        Wt3[t] = f2bf(Wout[(size_t)k * 512 + n]);
    }
}

// ---------------- m97-style bf16 GEMM: C = A(MxK) * Bt(NxK)^T -------------------
template <bool BF16OUT>
__global__ __launch_bounds__(256) void gemm_bt(const USHORT* __restrict__ A,
                                               const USHORT* __restrict__ Bt,
                                               void* __restrict__ Cv,
                                               int M, int N, int K) {
    __shared__ __align__(16) USHORT Asm[128 * 32];
    __shared__ __align__(16) USHORT Bsm[128 * 32];
    const int tid = threadIdx.x;
    const int wv = tid >> 6, ln = tid & 63;
    const int l16 = ln & 15, quad = ln >> 4;
    const int m0 = blockIdx.x * 128, n0 = blockIdx.y * 128;
    const int wm = (wv >> 1) * 64, wn = (wv & 1) * 64;

    f32x4 acc[4][4];
#pragma unroll
    for (int i = 0; i < 4; ++i)
#pragma unroll
        for (int j = 0; j < 4; ++j) acc[i][j] = fz4();

    const int kTiles = K >> 5;
    for (int kt = 0; kt < kTiles; ++kt) {
        __syncthreads();
#pragma unroll
        for (int i = 0; i < 2; ++i) {
            int cb = wv * 128 + i * 64;
            int c = cb + ln;
            gload_lds16(A + (size_t)(m0 + (c >> 2)) * K + kt * 32 + (c & 3) * 8,
                        &Asm[cb * 8]);
            gload_lds16(Bt + (size_t)(n0 + (c >> 2)) * K + kt * 32 + (c & 3) * 8,
                        &Bsm[cb * 8]);
        }
        __syncthreads();

        bf16x8 af[4], bfr[4];
#pragma unroll
        for (int i = 0; i < 4; ++i)
            af[i] = ldbf8(&Asm[(wm + i * 16 + l16) * 32 + quad * 8]);
#pragma unroll
        for (int j = 0; j < 4; ++j)
            bfr[j] = ldbf8(&Bsm[(wn + j * 16 + l16) * 32 + quad * 8]);
#pragma unroll
        for (int i = 0; i < 4; ++i)
#pragma unroll
            for (int j = 0; j < 4; ++j)
                acc[i][j] = mfma16(af[i], bfr[j], acc[i][j]);
    }

#pragma unroll
    for (int i = 0; i < 4; ++i)
#pragma unroll
        for (int j = 0; j < 4; ++j)
#pragma unroll
            for (int r = 0; r < 4; ++r) {
                size_t row = m0 + wm + i * 16 + quad * 4 + r;
                size_t col = n0 + wn + j * 16 + l16;
                if (BF16OUT)
                    ((USHORT*)Cv)[row * N + col] = f2bf(acc[i][j][r]);
                else
                    ((float*)Cv)[row * N + col] = acc[i][j][r];
            }
}

// ---------------- V transpose: Vt[((b*8+h)*64+d)*1024+k] = P[(b*1024+k)*640+(h+2)*64+d]
__global__ __launch_bounds__(256) void transpose_v(const USHORT* __restrict__ P,
                                                   USHORT* __restrict__ Vt) {
    __shared__ __align__(16) USHORT T[64][72];
    const int t = threadIdx.x;
    const int k0 = blockIdx.x * 64;
    const int hh = blockIdx.y;
    const int b = blockIdx.z;
#pragma unroll
    for (int i = 0; i < 2; ++i) {
        int c = i * 256 + t;
        int kk = c >> 3, d8 = (c & 7) * 8;
        u16x8 v = *(const u16x8*)(P + (size_t)((b << 10) + k0 + kk) * 640 +
                                  (hh + 2) * 64 + d8);
        *(u16x8*)&T[kk][d8] = v;
    }
    __syncthreads();
#pragma unroll
    for (int i = 0; i < 2; ++i) {
        int d = (t >> 3) + i * 32;
        int kk0 = (t & 7) * 8;
        u16x8 v;
#pragma unroll
        for (int j = 0; j < 8; ++j) v[j] = T[kk0 + j][d];
        *(u16x8*)(Vt + (size_t)(((b << 3) + hh) * 64 + d) * 1024 + k0 + kk0) = v;
    }
}

// ---------------- fused attention v7: wave-per-batch --------------------------
// grid (qt=64, h=8) x 512 thr (8 waves). Wave b owns batch b for this
// (head, 16-q tile) and walks ALL 1024 keys in 16 steps of 64 -> kc=1:
// every output element computed once, no atomics, no ctx zero, bf16 out.
// Cross-batch softmax = LDS exchange inside the WG:
//   each wave writes exp(scores) pair-packed bf16 to Ebuf[b][kk][q];
//   phase1: thread t sums Ebuf over b for (kk,q)=(t>>4,t&15) -> invZ (rcp);
//   phase2: wave rescales its register-resident e by invZ, packs the PV
//   B-operand directly (C-layout == K=16 B-layout identity), A = V^T 8B frags.
// Per-wave state ~90 VGPR (sacc 16 + oacc 16 + qf 8 + kf 32 transient) ->
// no spill at the 128-reg cap of 4 waves/SIMD.
__global__ __launch_bounds__(512, 4) void attn_kernel(const USHORT* __restrict__ P,
                                                      const USHORT* __restrict__ Vt,
                                                      USHORT* __restrict__ ctxb) {
    __shared__ unsigned Ebuf[8][32][17];   // pair-packed bf16x2, +1 pad
    __shared__ float2  invZb[32][17];

    const int qt = blockIdx.x, h = blockIdx.y;
    const int tid = threadIdx.x;
    const int b = tid >> 6, ln = tid & 63;
    const int l16 = ln & 15, quad = ln >> 4;
    const int q0 = qt * 16;

    // resident Q fragments (B-operand K=32: n=q=l16, k=d=quad*8+j)
    const USHORT* qp = P + (size_t)((b << 10) + q0 + l16) * 640 + h * 64 + quad * 8;
    const bf16x8 qf0 = ldbf8(qp);
    const bf16x8 qf1 = ldbf8(qp + 32);

    // K fragment base (A-operand: m=key=l16 within tile, k=d=quad*8+j)
    const USHORT* kbase = P + (size_t)((b << 10) + l16) * 640 + (h + 1) * 64 + quad * 8;
    // V^T fragment base (A-operand of PV: m=d=l16 within tile, k=key=quad*4+j)
    const USHORT* vbase = Vt + (size_t)(((b << 3) + h) * 64 + l16) * 1024 + quad * 4;

    f32x4 oacc[4];
#pragma unroll
    for (int nt = 0; nt < 4; ++nt) oacc[nt] = fz4();

    for (int it = 0; it < 16; ++it) {
        const int k0 = it * 64;

        // ---- scores S^T for 4 key-tiles: e[kt] C-layout (col=q, row=key) ----
        bf16x8 kf[8];
#pragma unroll
        for (int kt = 0; kt < 4; ++kt) {
            const USHORT* kp = kbase + (size_t)(k0 + kt * 16) * 640;
            kf[kt * 2]     = ldbf8(kp);
            kf[kt * 2 + 1] = ldbf8(kp + 32);
        }
        f32x4 e[4];
#pragma unroll
        for (int kt = 0; kt < 4; ++kt) {
            f32x4 s = mfma16(kf[kt * 2], qf0, fz4());
            e[kt] = mfma16(kf[kt * 2 + 1], qf1, s);
        }

        // ---- exp2 in place (scale folded; no max pass needed, |arg|<2) ----
#pragma unroll
        for (int kt = 0; kt < 4; ++kt)
#pragma unroll
            for (int r = 0; r < 4; ++r)
                e[kt][r] = __builtin_amdgcn_exp2f(e[kt][r] * 0.1803368801f);

        // ---- publish e pair-packed along key: kk = key>>1 ----
#pragma unroll
        for (int kt = 0; kt < 4; ++kt) {
            Ebuf[b][kt * 8 + quad * 2 + 0][l16] = pack2bf(e[kt][0], e[kt][1]);
            Ebuf[b][kt * 8 + quad * 2 + 1][l16] = pack2bf(e[kt][2], e[kt][3]);
        }
        __syncthreads();

        // ---- phase1: Z over batches; 512 threads cover 32 kk x 16 q ----
        {
            const int kk = tid >> 4, q = tid & 15;
            float z0 = 0.f, z1 = 0.f;
#pragma unroll
            for (int bb = 0; bb < 8; ++bb) {
                unsigned u = Ebuf[bb][kk][q];
                z0 += bflo(u);
                z1 += bfhi(u);
            }
            invZb[kk][q] = float2{__builtin_amdgcn_rcpf(z0),
                                  __builtin_amdgcn_rcpf(z1)};
        }
        __syncthreads();

        // ---- phase2: rescale register e -> PV B-operand; A = V^T 8B frags ----
#pragma unroll
        for (int kt = 0; kt < 4; ++kt) {
            float2 z0 = invZb[kt * 8 + quad * 2 + 0][l16];
            float2 z1 = invZb[kt * 8 + quad * 2 + 1][l16];
            union { unsigned u[2]; bf16x4 v; } at;
            at.u[0] = pack2bf(e[kt][0] * z0.x, e[kt][1] * z0.y);
            at.u[1] = pack2bf(e[kt][2] * z1.x, e[kt][3] * z1.y);
            const USHORT* vp = vbase + k0 + kt * 16;
#pragma unroll
            for (int nt = 0; nt < 4; ++nt) {
                bf16x4 vf = *(const bf16x4*)(vp + (size_t)(nt * 16) * 1024);
                oacc[nt] = mfma16k16(vf, at.v, oacc[nt]);
            }
        }
        __syncthreads();  // Ebuf reused next step (phase1 reads done)
    }

    // ---- epilogue: O C-layout (col=q=l16, row=d=quad*4+r) -> bf16, 8B stores ----
    USHORT* op = ctxb + (size_t)((b << 10) + q0 + l16) * 512 + h * 64 + quad * 4;
#pragma unroll
    for (int nt = 0; nt < 4; ++nt) {
        uint2 pk;
        pk.x = pack2bf(oacc[nt][0], oacc[nt][1]);
        pk.y = pack2bf(oacc[nt][2], oacc[nt][3]);
        *(uint2*)(op + nt * 16) = pk;
    }
}

extern "C" void kernel_launch(void* const* d_in, const int* in_sizes, int n_in,
                              void* d_out, int out_size, void* d_ws, size_t ws_size,
                              hipStream_t stream) {
    const float* X = (const float*)d_in[0];     // (8,1024,512)
    const float* Wqkv = (const float*)d_in[1];  // (512,1536) — only cols 0..639 used
    const float* Wout = (const float*)d_in[2];  // (512,512)
    float* out = (float*)d_out;                 // (8,1024,512) fp32

    char* w = (char*)d_ws;
    USHORT* Xb   = (USHORT*)(w);              //  8,388,608 B
    USHORT* Wt1  = (USHORT*)(w + 8388608);    //    655,360 B  (640x512)
    USHORT* Wt3  = (USHORT*)(w + 9043968);    //    524,288 B  (512x512)
    USHORT* P    = (USHORT*)(w + 9568256);    // 10,485,760 B  (8192x640 bf16)
    USHORT* Vt   = (USHORT*)(w + 20054016);   //  8,388,608 B  (8x8x64x1024 bf16)
    USHORT* CtxB = (USHORT*)(w + 28442624);   //  8,388,608 B  (8192x512 bf16)

    prep_kernel<<<4352, 256, 0, stream>>>(X, Wqkv, Wout, Xb, Wt1, Wt3);
    // P = Xb @ Wqkv[:, :640]
    gemm_bt<true><<<dim3(64, 5), 256, 0, stream>>>(Xb, Wt1, (void*)P, 8192, 640, 512);
    transpose_v<<<dim3(16, 8, 8), 256, 0, stream>>>(P, Vt);
    attn_kernel<<<dim3(64, 8), 512, 0, stream>>>(P, Vt, CtxB);
    // out = CtxB @ W_out
    gemm_bt<false><<<dim3(64, 4), 256, 0, stream>>>(CtxB, Wt3, (void*)out, 8192, 512, 512);
}